// Round 1
// baseline (156.954 us; speedup 1.0000x reference)
//
#include <hip/hip_runtime.h>
#include <math.h>

// Problem constants (from reference): B=2, C=1, H=W=2048, RADIUS=1, RK=3
namespace {
constexpr int H = 2048;
constexpr int W = 2048;
constexpr int NPIX = H * W;            // 2^22
constexpr int B = 2;
constexpr double DEC = 0.95;
constexpr double OMD = 1.0 - 0.95;
}

// One thread handles 4 consecutive pixels (float4 lane width = 16B).
// J plane k (k = i*3+j) multiplies neighbor s[(h+i-1)%H, (w+j-1)%W].
// Center plane (k=4) is zeroed in setup -> skipped entirely (saves 134 MB read).
__global__ __launch_bounds__(256) void ising_step_kernel(
    const float* __restrict__ x,      // (B, 2, H, W): s then b
    const float* __restrict__ obvs,   // (B, 4, H, W): e, e2, c, m
    const float* __restrict__ Jm,     // (1, 9, N)
    const float* __restrict__ rs,     // (B, 1, H, W)
    const float* __restrict__ rd,     // (1, 1, H, W)
    float* __restrict__ out)          // state (B,2,H,W) ++ obvs_out (B,4,H,W)
{
  const int tid = blockIdx.x * blockDim.x + threadIdx.x;
  constexpr int QPI = NPIX >> 2;           // quads per image = 2^20
  const int bi = tid >> 20;                // batch index (QPI = 2^20)
  const int q  = tid & (QPI - 1);
  const int n0 = q << 2;                   // first pixel of the quad
  const int h  = n0 >> 11;                 // W = 2^11
  const int w0 = n0 & (W - 1);

  const float* sbase = x + (size_t)bi * 2 * NPIX;
  const float* bbase = sbase + NPIX;

  const int hm = (h - 1) & (H - 1);
  const int hp = (h + 1) & (H - 1);
  const float* rowm = sbase + (size_t)hm * W;
  const float* rowc = sbase + (size_t)h  * W;
  const float* rowp = sbase + (size_t)hp * W;

  const float4 vm = *(const float4*)(rowm + w0);
  const float4 vc = *(const float4*)(rowc + w0);
  const float4 vp = *(const float4*)(rowp + w0);
  const int wl = (w0 - 1) & (W - 1);       // wrap only matters at w0==0
  const int wr = (w0 + 4) & (W - 1);       // wrap only matters at w0==2044
  const float am[6] = {rowm[wl], vm.x, vm.y, vm.z, vm.w, rowm[wr]};
  const float ac[6] = {rowc[wl], vc.x, vc.y, vc.z, vc.w, rowc[wr]};
  const float ap[6] = {rowp[wl], vp.x, vp.y, vp.z, vp.w, rowp[wr]};

  // 8 non-center J planes, float4 each
  float Jq[8][4];
  #pragma unroll
  for (int k = 0; k < 8; ++k) {
    const int kk = (k < 4) ? k : (k + 1);  // skip center plane 4
    const float4 jv = *(const float4*)(Jm + (size_t)kk * NPIX + n0);
    Jq[k][0] = jv.x; Jq[k][1] = jv.y; Jq[k][2] = jv.z; Jq[k][3] = jv.w;
  }

  const float4 bv  = *(const float4*)(bbase + n0);
  const float* ob  = obvs + (size_t)bi * 4 * NPIX;
  const float4 ev  = *(const float4*)(ob + n0);
  const float4 e2v = *(const float4*)(ob + (size_t)NPIX + n0);
  const float4 cvv = *(const float4*)(ob + (size_t)2 * NPIX + n0);
  const float4 mv  = *(const float4*)(ob + (size_t)3 * NPIX + n0);
  const float4 rsv = *(const float4*)(rs + (size_t)bi * NPIX + n0);
  const float4 rdv = *(const float4*)(rd + n0);

  const float scq[4] = {vc.x, vc.y, vc.z, vc.w};
  const float bq[4]  = {bv.x, bv.y, bv.z, bv.w};
  const float eq[4]  = {ev.x, ev.y, ev.z, ev.w};
  const float e2q[4] = {e2v.x, e2v.y, e2v.z, e2v.w};
  const float cq[4]  = {cvv.x, cvv.y, cvv.z, cvv.w};
  const float mq[4]  = {mv.x, mv.y, mv.z, mv.w};
  const float rsq[4] = {rsv.x, rsv.y, rsv.z, rsv.w};
  const float rdq[4] = {rdv.x, rdv.y, rdv.z, rdv.w};

  float so[4], eo[4], e2o[4], co[4], mo[4];
  #pragma unroll
  for (int t = 0; t < 4; ++t) {
    // dot in double: minimizes the window where our Metropolis decision
    // can disagree with the reference at the rand_s < p boundary
    const double sum =
        (double)Jq[0][t] * am[t]     + (double)Jq[1][t] * am[t + 1] +
        (double)Jq[2][t] * am[t + 2] + (double)Jq[3][t] * ac[t]     +
        (double)Jq[4][t] * ac[t + 2] + (double)Jq[5][t] * ap[t]     +
        (double)Jq[6][t] * ap[t + 1] + (double)Jq[7][t] * ap[t + 2];
    const double s  = (double)scq[t];
    const double de = 2.0 * s * sum;
    const double E  = -s * sum;
    const double b  = (double)bq[t];
    const double en  = DEC * (double)eq[t]  + OMD * E;
    const double e2n = DEC * (double)e2q[t] + OMD * E * E;
    const double cn  = DEC * (double)cq[t]  + OMD * (e2n - en * en) * b * b;
    const double mn  = DEC * (double)mq[t]  + OMD * s;
    const double p   = (de <= 0.0) ? 1.0 : exp(-de * b);
    const bool acc   = ((double)rsq[t] < p) && (rdq[t] > 0.5f);
    so[t]  = (float)(acc ? -s : s);
    eo[t]  = (float)en;
    e2o[t] = (float)e2n;
    co[t]  = (float)cn;
    mo[t]  = (float)mn;
  }

  float* st = out + (size_t)bi * 2 * NPIX;
  *(float4*)(st + n0)        = make_float4(so[0], so[1], so[2], so[3]);
  *(float4*)(st + NPIX + n0) = bv;

  float* oo = out + (size_t)B * 2 * NPIX + (size_t)bi * 4 * NPIX;
  *(float4*)(oo + n0)                    = make_float4(eo[0], eo[1], eo[2], eo[3]);
  *(float4*)(oo + (size_t)NPIX + n0)     = make_float4(e2o[0], e2o[1], e2o[2], e2o[3]);
  *(float4*)(oo + (size_t)2 * NPIX + n0) = make_float4(co[0], co[1], co[2], co[3]);
  *(float4*)(oo + (size_t)3 * NPIX + n0) = make_float4(mo[0], mo[1], mo[2], mo[3]);
}

extern "C" void kernel_launch(void* const* d_in, const int* in_sizes, int n_in,
                              void* d_out, int out_size, void* d_ws, size_t ws_size,
                              hipStream_t stream) {
  const float* x    = (const float*)d_in[0];
  const float* obvs = (const float*)d_in[1];
  const float* Jm   = (const float*)d_in[2];
  const float* rs   = (const float*)d_in[3];
  const float* rd   = (const float*)d_in[4];
  float* out = (float*)d_out;

  constexpr int total_quads = B * NPIX / 4;   // 2,097,152
  constexpr int block = 256;
  constexpr int grid = total_quads / block;   // 8192
  ising_step_kernel<<<grid, block, 0, stream>>>(x, obvs, Jm, rs, rd, out);
}